// Round 4
// baseline (484.871 us; speedup 1.0000x reference)
//
#include <hip/hip_runtime.h>

typedef _Float16 f16;
typedef __attribute__((ext_vector_type(4))) _Float16 f16x4;
typedef __attribute__((ext_vector_type(8))) _Float16 f16x8;
typedef __attribute__((ext_vector_type(4))) float f32x4;

#define B_ 8192
#define D_ 784
#define H_ 1024
#define L_ 128
#define T_ 10
#define KP1 896          // D padded to multiple of 64
#define NPH 1024         // head N padded to 1024 (4 x 256 tiles)
#define MAXTILES (B_/128 + T_)   // 74  (128-row map, for enc3 kernel)
#define MAXT256 (B_/256 + T_)    // 42  (256-row map)
#define PADROWS 256

// ctrl int indices
#define C_COUNT 0
#define C_CURS 16
#define C_OFFS 32        // 17 entries
#define C_NTILES 49
#define C_NTILES2 50
#define C_TTASK 64       // 80 entries (128-map)
#define C_TROW 160       // 80 entries
#define C_TTASK2 256     // 48 entries (256-map)
#define C_TROW2 320      // 48 entries

__global__ void k_init(int* ctrl) {
    if (threadIdx.x < 64) ctrl[threadIdx.x] = 0;
}

__global__ void k_count(const int* __restrict__ task, int* __restrict__ ctrl) {
    int b = blockIdx.x * 256 + threadIdx.x;
    if (b < B_) atomicAdd(&ctrl[C_COUNT + task[b]], 1);
}

__global__ void k_scan(int* ctrl) {
    if (threadIdx.x == 0 && blockIdx.x == 0) {
        int off = 0;
        ctrl[C_OFFS] = 0;
        for (int t = 0; t < T_; ++t) { off += ctrl[C_COUNT + t]; ctrl[C_OFFS + t + 1] = off; }
        int nt = 0;
        for (int t = 0; t < T_; ++t)
            for (int r = ctrl[C_OFFS + t]; r < ctrl[C_OFFS + t + 1]; r += 128) {
                ctrl[C_TTASK + nt] = t; ctrl[C_TROW + nt] = r; ++nt;
            }
        ctrl[C_NTILES] = nt;
        int nt2 = 0;
        for (int t = 0; t < T_; ++t)
            for (int r = ctrl[C_OFFS + t]; r < ctrl[C_OFFS + t + 1]; r += 256) {
                ctrl[C_TTASK2 + nt2] = t; ctrl[C_TROW2 + nt2] = r; ++nt2;
            }
        ctrl[C_NTILES2] = nt2;
    }
}

__global__ void k_scatter(const int* __restrict__ task, int* __restrict__ ctrl, int* __restrict__ perm) {
    int b = blockIdx.x * 256 + threadIdx.x;
    if (b >= B_) return;
    int t = task[b];
    int i = ctrl[C_OFFS + t] + atomicAdd(&ctrl[C_CURS + t], 1);
    perm[i] = b;
}

// gather + fp32->f16, vectorized
__global__ void k_gather_x(const float* __restrict__ x, const int* __restrict__ perm, f16* __restrict__ Xp) {
    int i = blockIdx.x;
    int r = perm[i];
    int c = threadIdx.x * 4;
    if (c >= KP1) return;
    f16x4 o = (f16x4){0, 0, 0, 0};
    if (c < D_) {
        float4 v = *(const float4*)(x + (long)r * D_ + c);
        o[0] = (f16)v.x; o[1] = (f16)v.y; o[2] = (f16)v.z; o[3] = (f16)v.w;
    }
    *(f16x4*)(Xp + (long)i * KP1 + c) = o;
}

// transpose-convert: src fp32 [T][K][N] -> dst f16 [T][Np][Kp], zero-padded.
__global__ void k_convW(const float* __restrict__ src, f16* __restrict__ dst,
                        int K, int N, int Kp, int Np) {
    __shared__ float tile[64][65];
    int k0 = blockIdx.x * 64, n0 = blockIdx.y * 64, t = blockIdx.z;
    const float* s = src + (long)t * K * N;
    f16* d = dst + (long)t * Np * Kp;
    int tid = threadIdx.x;
    int r = tid >> 2;
    int cb = (tid & 3) * 16;
    int gk = k0 + r;
#pragma unroll
    for (int j = 0; j < 4; ++j) {
        int gn = n0 + cb + j * 4;
        float4 v = {0.f, 0.f, 0.f, 0.f};
        if (gk < K) {
            const float* p = s + (long)gk * N + gn;
            if (gn + 3 < N) v = *(const float4*)p;
            else {
                if (gn + 0 < N) v.x = p[0];
                if (gn + 1 < N) v.y = p[1];
                if (gn + 2 < N) v.z = p[2];
                if (gn + 3 < N) v.w = p[3];
            }
        }
        tile[r][cb + j * 4 + 0] = v.x;
        tile[r][cb + j * 4 + 1] = v.y;
        tile[r][cb + j * 4 + 2] = v.z;
        tile[r][cb + j * 4 + 3] = v.w;
    }
    __syncthreads();
    int n = n0 + r;
#pragma unroll
    for (int j = 0; j < 2; ++j) {
        int kk = cb + j * 8;
        f16x8 o;
#pragma unroll
        for (int u = 0; u < 8; ++u) o[u] = (f16)tile[kk + u][r];
        if (n < Np) *(f16x8*)(d + (long)n * Kp + k0 + kk) = o;
    }
}

// z = mu + exp(ls) * eps  (permuted rows)
__global__ void k_z(const float* __restrict__ mu, const float* __restrict__ ls,
                    const float* __restrict__ eps, const int* __restrict__ perm,
                    f16* __restrict__ Z) {
    long gid = (long)blockIdx.x * 256 + threadIdx.x;
    int i = (int)(gid >> 7), c = (int)(gid & 127);
    int r = perm[i];
    float m = mu[(long)r * L_ + c];
    float l = ls[(long)r * L_ + c];
    Z[(long)i * L_ + c] = (f16)(m + __expf(l) * eps[(long)r * L_ + c]);
}

// ---------------------------------------------------------------------------
// 256x256 8-phase grouped GEMM (T1+T2+T3+T4+T5), BK=32 pair-buffered.
// LDS: 16 regions x 8KB: region(buf,tau,op,half). 128 KiB total.
// 8 waves (2M x 4N), per-wave output 128x64, acc = 8x4 frags of 16x16.
// Swizzle: LDS(row, chunk_slot) holds global chunk (chunk_slot ^ (row&3));
// stage uses inverse-swizzled global source (linear LDS dest), reads XOR.
// vmcnt(4) at phases 4/8: drains exactly the next K-tile's 4 staging calls.
// ---------------------------------------------------------------------------
#define LDSB(buf,tau,op,half) (((((buf)*2+(tau))*2+(op))*2+(half))*8192)

template <int EPI, bool GROUPED>
__global__ __launch_bounds__(512, 1)
void k_gemm256(const f16* __restrict__ A,
               const f16* __restrict__ W, long wstride,
               const float* __restrict__ bias, int bstride,
               int K, int N,
               f16* __restrict__ outF16, float* __restrict__ o0,
               const int* __restrict__ ctrl, const int* __restrict__ perm) {
    extern __shared__ char lds[];
    int tid = threadIdx.x, lane = tid & 63;
    int wave = tid >> 6, wm = wave >> 2, wn = wave & 3;

    // T1: bijective XCD swizzle (host guarantees gridDim.x % 8 == 0)
    int cpx = gridDim.x >> 3;
    int wgid = (blockIdx.x & 7) * cpx + (blockIdx.x >> 3);
    int tm = wgid >> 2, tn = wgid & 3;

    int t, row0, mrows;
    if (GROUPED) {
        if (tm >= ctrl[C_NTILES2]) return;
        t = ctrl[C_TTASK2 + tm];
        row0 = ctrl[C_TROW2 + tm];
        mrows = min(256, ctrl[C_OFFS + t + 1] - row0);
    } else {
        t = 0; row0 = tm * 256; mrows = 256;
    }
    const f16* Wt = W + (long)t * wstride;
    const float* bt = bias + (long)t * bstride;
    int n0 = tn * 256;

    const f16* src01 = A + (long)row0 * K;
    const f16* src1  = A + (long)(row0 + 128) * K;
    const f16* src2  = Wt + (long)n0 * K;
    const f16* src3  = Wt + (long)(n0 + 128) * K;

    // staging source mapping: thread g writes LDS flat byte g*16 of the 8KB
    // half-tile; that slot is logical (row g>>2, chunk_slot g&3), whose global
    // chunk is (g&3)^(row&3) (inverse swizzle).
    int rho = tid >> 2;
    long srcOff = (long)rho * K + (((tid & 3) ^ (rho & 3)) << 3);
    int dstOff = (tid >> 6) << 10;   // wave-uniform; HW adds lane*16

    f32x4 acc[8][4];
#pragma unroll
    for (int i = 0; i < 8; ++i)
#pragma unroll
        for (int j = 0; j < 4; ++j) acc[i][j] = (f32x4){0.f, 0.f, 0.f, 0.f};

    auto STAGE = [&](int bufN, int p, int ktile) {
        int op = (p >> 1) & 1, half = p & 1, tau = p >> 2;
        const f16* s = (op ? (half ? src3 : src2) : (half ? src1 : src01)) + srcOff + ktile * 32;
        __builtin_amdgcn_global_load_lds(
            (const __attribute__((address_space(1))) unsigned int*)s,
            (__attribute__((address_space(3))) unsigned int*)(lds + LDSB(bufN, tau, op, half) + dstOff),
            16, 0, 0);
    };

    int NI = K >> 6;   // pairs of K-tiles
    // prologue: stage pair 0 (k-tiles 0,1), 8 calls
#pragma unroll
    for (int p = 0; p < 8; ++p) STAGE(0, p, p >> 2);
    asm volatile("s_waitcnt vmcnt(4)" ::: "memory");   // k-tile 0 landed
    asm volatile("s_barrier" ::: "memory");

    for (int i = 0; i < NI; ++i) {
        int b = i & 1, bn = b ^ 1;
        bool last = (i == NI - 1);
        int kt2 = (i + 1) * 2;
#pragma unroll
        for (int p = 0; p < 8; ++p) {
            const int tau = p >> 2, q = p & 3, qm = q & 1, qn = q >> 1;
            // ds-load register subtiles (6 x ds_read_b128), swizzled
            f16x8 af[4], bf[2];
            {
                int ab = LDSB(b, tau, 0, 0) + wm * 8192;
#pragma unroll
                for (int mi = 0; mi < 4; ++mi) {
                    int rr = qm * 64 + mi * 16 + (lane & 15);
                    af[mi] = *(const f16x8*)(lds + ab + rr * 64 + ((((lane >> 4)) ^ (rr & 3)) << 4));
                }
                int bb = LDSB(b, tau, 1, 0) + (wn >> 1) * 8192;
#pragma unroll
                for (int nj = 0; nj < 2; ++nj) {
                    int rr = (wn & 1) * 64 + qn * 32 + nj * 16 + (lane & 15);
                    bf[nj] = *(const f16x8*)(lds + bb + rr * 64 + ((((lane >> 4)) ^ (rr & 3)) << 4));
                }
            }
            // stage 1 half-tile of the next pair
            if (!last) STAGE(bn, p, kt2 + tau);
            asm volatile("s_barrier" ::: "memory");
            asm volatile("s_waitcnt lgkmcnt(0)" ::: "memory");
            __builtin_amdgcn_sched_barrier(0);
            __builtin_amdgcn_s_setprio(1);
#pragma unroll
            for (int mi = 0; mi < 4; ++mi)
#pragma unroll
                for (int nj = 0; nj < 2; ++nj)
                    acc[qm * 4 + mi][qn * 2 + nj] = __builtin_amdgcn_mfma_f32_16x16x32_f16(
                        af[mi], bf[nj], acc[qm * 4 + mi][qn * 2 + nj], 0, 0, 0);
            __builtin_amdgcn_s_setprio(0);
            if (q == 3) {
                if (last) asm volatile("s_waitcnt vmcnt(0)" ::: "memory");
                else      asm volatile("s_waitcnt vmcnt(4)" ::: "memory");
            }
            asm volatile("s_barrier" ::: "memory");
        }
    }

    // epilogue
    int cq = lane >> 4, cr = lane & 15;
#pragma unroll
    for (int mi = 0; mi < 8; ++mi) {
#pragma unroll
        for (int nj = 0; nj < 4; ++nj) {
#pragma unroll
            for (int reg = 0; reg < 4; ++reg) {
                int rl = wm * 128 + mi * 16 + cq * 4 + reg;
                if (rl >= mrows) continue;
                int gcol = n0 + wn * 64 + nj * 16 + cr;
                if (gcol >= N) continue;
                float v = acc[mi][nj][reg] + bt[gcol];
                int grow = row0 + rl;
                if (EPI == 0) {
                    outF16[(long)grow * H_ + gcol] = (f16)(v > 0.f ? v : 0.f);
                } else {
                    o0[(long)perm[grow] * D_ + gcol] = 1.f / (1.f + __expf(-v));
                }
            }
        }
    }
}

// 128x128 2-phase kernel (kept for enc3: N=256). EPI 1: mu/ls scatter fp32.
template <int EPI, bool GROUPED>
__global__ __launch_bounds__(256)
void k_gemm(const f16* __restrict__ A,
            const f16* __restrict__ W, long wstride,
            const float* __restrict__ bias, int bstride,
            int K, int N,
            f16* __restrict__ outF16,
            float* __restrict__ o0, float* __restrict__ o1,
            const int* __restrict__ ctrl, const int* __restrict__ perm) {
    __shared__ f16 sA[2 * 8192];
    __shared__ f16 sB[2 * 8192];
    int tid = threadIdx.x;
    int lane = tid & 63, wave = tid >> 6;
    int wm = wave >> 1, wn = wave & 1;
    int n0 = blockIdx.x * 128;

    int t, row0, mrows;
    if (GROUPED) {
        int nt = ctrl[C_NTILES];
        if ((int)blockIdx.y >= nt) return;
        t = ctrl[C_TTASK + blockIdx.y];
        row0 = ctrl[C_TROW + blockIdx.y];
        mrows = min(128, ctrl[C_OFFS + t + 1] - row0);
    } else {
        t = 0; row0 = blockIdx.y * 128; mrows = 128;
    }
    const f16* Wt = W + (long)t * wstride;
    const float* bt = bias + (long)t * bstride;

    int srow = tid >> 3, scol = (tid & 7) << 3;

    f32x4 acc[4][4];
#pragma unroll
    for (int i = 0; i < 4; ++i)
#pragma unroll
        for (int j = 0; j < 4; ++j) acc[i][j] = (f32x4){0.f, 0.f, 0.f, 0.f};

    auto stage = [&](int buf, int kt) {
        int k0 = kt << 6;
        const f16* Ab = A + (long)row0 * K + k0;
        const f16* Bb = Wt + (long)n0 * K + k0;
#pragma unroll
        for (int rr = 0; rr < 4; ++rr) {
            __builtin_amdgcn_global_load_lds(
                (const __attribute__((address_space(1))) unsigned int*)(Ab + (long)(srow + 32 * rr) * K + scol),
                (__attribute__((address_space(3))) unsigned int*)(sA + buf * 8192 + rr * 2048 + wave * 512),
                16, 0, 0);
            __builtin_amdgcn_global_load_lds(
                (const __attribute__((address_space(1))) unsigned int*)(Bb + (long)(srow + 32 * rr) * K + scol),
                (__attribute__((address_space(3))) unsigned int*)(sB + buf * 8192 + rr * 2048 + wave * 512),
                16, 0, 0);
        }
    };

    auto compute = [&](int buf) {
        const f16* bA = sA + buf * 8192;
        const f16* bB = sB + buf * 8192;
#pragma unroll
        for (int kk = 0; kk < 2; ++kk) {
            f16x8 af[4], bf[4];
            int ko = kk * 32 + ((lane >> 4) << 3);
#pragma unroll
            for (int mi = 0; mi < 4; ++mi)
                af[mi] = *(const f16x8*)(bA + (wm * 64 + mi * 16 + (lane & 15)) * 64 + ko);
#pragma unroll
            for (int nj = 0; nj < 4; ++nj)
                bf[nj] = *(const f16x8*)(bB + (wn * 64 + nj * 16 + (lane & 15)) * 64 + ko);
#pragma unroll
            for (int mi = 0; mi < 4; ++mi)
#pragma unroll
                for (int nj = 0; nj < 4; ++nj)
                    acc[mi][nj] = __builtin_amdgcn_mfma_f32_16x16x32_f16(af[mi], bf[nj], acc[mi][nj], 0, 0, 0);
        }
    };

    int nk = K >> 6;
    stage(0, 0);
    __syncthreads();
    int cur = 0;
    for (int kt = 0; kt + 1 < nk; ++kt) {
        stage(cur ^ 1, kt + 1);
        compute(cur);
        __syncthreads();
        cur ^= 1;
    }
    compute(cur);

    int cq = lane >> 4;
    int cr = lane & 15;
#pragma unroll
    for (int mi = 0; mi < 4; ++mi) {
#pragma unroll
        for (int nj = 0; nj < 4; ++nj) {
#pragma unroll
            for (int reg = 0; reg < 4; ++reg) {
                int rl = wm * 64 + mi * 16 + cq * 4 + reg;
                int cl = wn * 64 + nj * 16 + cr;
                if (rl >= mrows) continue;
                int gcol = n0 + cl;
                if (gcol >= N) continue;
                float v = acc[mi][nj][reg] + bt[gcol];
                int grow = row0 + rl;
                if (EPI == 0) {
                    outF16[(long)grow * H_ + gcol] = (f16)(v > 0.f ? v : 0.f);
                } else if (EPI == 1) {
                    int r = perm[grow];
                    if (gcol < L_) o0[(long)r * L_ + gcol] = v;
                    else o1[(long)r * L_ + (gcol - L_)] = v;
                } else {
                    int r = perm[grow];
                    o0[(long)r * D_ + gcol] = 1.f / (1.f + __expf(-v));
                }
            }
        }
    }
}

extern "C" void kernel_launch(void* const* d_in, const int* in_sizes, int n_in,
                              void* d_out, int out_size, void* d_ws, size_t ws_size,
                              hipStream_t stream) {
    const float* x   = (const float*)d_in[0];
    const float* eps = (const float*)d_in[1];
    const float* eW1 = (const float*)d_in[2];
    const float* eb1 = (const float*)d_in[3];
    const float* eW2 = (const float*)d_in[4];
    const float* eb2 = (const float*)d_in[5];
    const float* eW3 = (const float*)d_in[6];
    const float* eb3 = (const float*)d_in[7];
    const float* dW1 = (const float*)d_in[8];
    const float* db1 = (const float*)d_in[9];
    const float* dW2 = (const float*)d_in[10];
    const float* db2 = (const float*)d_in[11];
    const float* hW  = (const float*)d_in[12];
    const float* hb  = (const float*)d_in[13];
    const int* task  = (const int*)d_in[14];

    float* out = (float*)d_out;
    float* recon = out;
    float* mu = out + (size_t)B_ * D_;
    float* ls = mu + (size_t)B_ * L_;

    char* w = (char*)d_ws;
    size_t o = 0;
    auto alloc = [&](size_t bytes) -> char* {
        char* p = w + o;
        o = (o + bytes + 255) & ~(size_t)255;
        return p;
    };
    int* ctrl  = (int*)alloc(4096);
    int* perm  = (int*)alloc((size_t)B_ * 4);
    f16* Xp    = (f16*)alloc((size_t)(B_ + PADROWS) * KP1 * 2);
    f16* H1    = (f16*)alloc((size_t)(B_ + PADROWS) * H_ * 2);
    f16* H2    = (f16*)alloc((size_t)(B_ + PADROWS) * H_ * 2);
    f16* Z     = (f16*)alloc((size_t)(B_ + PADROWS) * L_ * 2);
    f16* Wt1   = (f16*)alloc((size_t)T_ * H_ * KP1 * 2);
    f16* Wt2   = (f16*)alloc((size_t)T_ * H_ * H_ * 2);
    f16* Wt3   = (f16*)alloc((size_t)T_ * 256 * H_ * 2);
    f16* WtD1  = (f16*)alloc((size_t)H_ * L_ * 2);
    f16* WtD2  = (f16*)alloc((size_t)H_ * H_ * 2);
    f16* WtH   = (f16*)alloc((size_t)T_ * NPH * H_ * 2);
    if (o > ws_size) return;

    // allow 128 KiB dynamic LDS on the 8-phase kernels
    (void)hipFuncSetAttribute((const void*)&k_gemm256<0, true>,  hipFuncAttributeMaxDynamicSharedMemorySize, 131072);
    (void)hipFuncSetAttribute((const void*)&k_gemm256<0, false>, hipFuncAttributeMaxDynamicSharedMemorySize, 131072);
    (void)hipFuncSetAttribute((const void*)&k_gemm256<2, true>,  hipFuncAttributeMaxDynamicSharedMemorySize, 131072);

    k_init<<<1, 64, 0, stream>>>(ctrl);
    k_count<<<B_ / 256, 256, 0, stream>>>(task, ctrl);
    k_scan<<<1, 1, 0, stream>>>(ctrl);
    k_scatter<<<B_ / 256, 256, 0, stream>>>(task, ctrl, perm);
    k_gather_x<<<B_, 256, 0, stream>>>(x, perm, Xp);

    k_convW<<<dim3(KP1 / 64, H_ / 64, T_), 256, 0, stream>>>(eW1, Wt1, D_, H_, KP1, H_);
    k_convW<<<dim3(H_ / 64, H_ / 64, T_), 256, 0, stream>>>(eW2, Wt2, H_, H_, H_, H_);
    k_convW<<<dim3(H_ / 64, 256 / 64, T_), 256, 0, stream>>>(eW3, Wt3, H_, 256, H_, 256);
    k_convW<<<dim3(L_ / 64, H_ / 64, 1), 256, 0, stream>>>(dW1, WtD1, L_, H_, L_, H_);
    k_convW<<<dim3(H_ / 64, H_ / 64, 1), 256, 0, stream>>>(dW2, WtD2, H_, H_, H_, H_);
    k_convW<<<dim3(H_ / 64, NPH / 64, T_), 256, 0, stream>>>(hW, WtH, H_, D_, H_, NPH);

    int gridG = MAXT256 * 4;    // 168, %8==0
    int gridD = (B_ / 256) * 4; // 128, %8==0

    // encoder layer 1: Xp(K=896) @ Wt1 -> relu -> H1
    k_gemm256<0, true><<<gridG, 512, 131072, stream>>>(
        Xp, Wt1, (long)H_ * KP1, eb1, H_, KP1, H_, H1, nullptr, ctrl, perm);
    // encoder layer 2: H1 @ Wt2 -> relu -> H2
    k_gemm256<0, true><<<gridG, 512, 131072, stream>>>(
        H1, Wt2, (long)H_ * H_, eb2, H_, H_, H_, H2, nullptr, ctrl, perm);
    // encoder layer 3 (N=256): 128^2 kernel, mu/ls scatter
    k_gemm<1, true><<<dim3(256 / 128, MAXTILES), 256, 0, stream>>>(
        H2, Wt3, (long)256 * H_, eb3, 256, H_, 256, nullptr, mu, ls, ctrl, perm);
    // z = mu + exp(ls)*eps
    k_z<<<(B_ * L_) / 256, 256, 0, stream>>>(mu, ls, eps, perm, Z);
    // decoder layer 1: Z(K=128) @ WtD1 -> relu -> H1
    k_gemm256<0, false><<<gridD, 512, 131072, stream>>>(
        Z, WtD1, 0, db1, 0, L_, H_, H1, nullptr, ctrl, perm);
    // decoder layer 2: H1 @ WtD2 -> relu -> H2
    k_gemm256<0, false><<<gridD, 512, 131072, stream>>>(
        H1, WtD2, 0, db2, 0, H_, H_, H2, nullptr, ctrl, perm);
    // head: H2 @ WtH -> sigmoid -> recon (scatter fp32)
    k_gemm256<2, true><<<gridG, 512, 131072, stream>>>(
        H2, WtH, (long)NPH * H_, hb, D_, H_, D_, nullptr, recon, ctrl, perm);
}

// Round 6
// 389.045 us; speedup vs baseline: 1.2463x; 1.2463x over previous
//
#include <hip/hip_runtime.h>

typedef _Float16 f16;
typedef __attribute__((ext_vector_type(4))) _Float16 f16x4;
typedef __attribute__((ext_vector_type(8))) _Float16 f16x8;
typedef __attribute__((ext_vector_type(4))) float f32x4;
typedef __attribute__((ext_vector_type(4))) int i32x4;

#define B_ 8192
#define D_ 784
#define H_ 1024
#define L_ 128
#define T_ 10
#define KP1 896          // D padded to multiple of 64
#define NPH 1024         // head N padded to 1024
#define MAXTILES (B_/128 + T_)   // 74  (128-row map, for enc3 kernel)
#define MAXT256 (B_/256 + T_)    // 42  (256-row map)
#define PADROWS 256
#define BUFB 49152       // 48KB per LDS buffer (A 32KB + B 16KB)

// ctrl int indices
#define C_COUNT 0
#define C_CURS 16
#define C_OFFS 32
#define C_NTILES 49
#define C_NTILES2 50
#define C_TTASK 64
#define C_TROW 160
#define C_TTASK2 256
#define C_TROW2 320

__global__ void k_init(int* ctrl) {
    if (threadIdx.x < 64) ctrl[threadIdx.x] = 0;
}

__global__ void k_count(const int* __restrict__ task, int* __restrict__ ctrl) {
    int b = blockIdx.x * 256 + threadIdx.x;
    if (b < B_) atomicAdd(&ctrl[C_COUNT + task[b]], 1);
}

__global__ void k_scan(int* ctrl) {
    if (threadIdx.x == 0 && blockIdx.x == 0) {
        int off = 0;
        ctrl[C_OFFS] = 0;
        for (int t = 0; t < T_; ++t) { off += ctrl[C_COUNT + t]; ctrl[C_OFFS + t + 1] = off; }
        int nt = 0;
        for (int t = 0; t < T_; ++t)
            for (int r = ctrl[C_OFFS + t]; r < ctrl[C_OFFS + t + 1]; r += 128) {
                ctrl[C_TTASK + nt] = t; ctrl[C_TROW + nt] = r; ++nt;
            }
        ctrl[C_NTILES] = nt;
        int nt2 = 0;
        for (int t = 0; t < T_; ++t)
            for (int r = ctrl[C_OFFS + t]; r < ctrl[C_OFFS + t + 1]; r += 256) {
                ctrl[C_TTASK2 + nt2] = t; ctrl[C_TROW2 + nt2] = r; ++nt2;
            }
        ctrl[C_NTILES2] = nt2;
    }
}

__global__ void k_scatter(const int* __restrict__ task, int* __restrict__ ctrl, int* __restrict__ perm) {
    int b = blockIdx.x * 256 + threadIdx.x;
    if (b >= B_) return;
    int t = task[b];
    int i = ctrl[C_OFFS + t] + atomicAdd(&ctrl[C_CURS + t], 1);
    perm[i] = b;
}

__global__ void k_gather_x(const float* __restrict__ x, const int* __restrict__ perm, f16* __restrict__ Xp) {
    int i = blockIdx.x;
    int r = perm[i];
    int c = threadIdx.x * 4;
    if (c >= KP1) return;
    f16x4 o = (f16x4){0, 0, 0, 0};
    if (c < D_) {
        float4 v = *(const float4*)(x + (long)r * D_ + c);
        o[0] = (f16)v.x; o[1] = (f16)v.y; o[2] = (f16)v.z; o[3] = (f16)v.w;
    }
    *(f16x4*)(Xp + (long)i * KP1 + c) = o;
}

// transpose-convert: src fp32 [T][K][N] -> dst f16 [T][Np][Kp], zero-padded.
__global__ void k_convW(const float* __restrict__ src, f16* __restrict__ dst,
                        int K, int N, int Kp, int Np) {
    __shared__ float tile[64][65];
    int k0 = blockIdx.x * 64, n0 = blockIdx.y * 64, t = blockIdx.z;
    const float* s = src + (long)t * K * N;
    f16* d = dst + (long)t * Np * Kp;
    int tid = threadIdx.x;
    int r = tid >> 2;
    int cb = (tid & 3) * 16;
    int gk = k0 + r;
#pragma unroll
    for (int j = 0; j < 4; ++j) {
        int gn = n0 + cb + j * 4;
        float4 v = {0.f, 0.f, 0.f, 0.f};
        if (gk < K) {
            const float* p = s + (long)gk * N + gn;
            if (gn + 3 < N) v = *(const float4*)p;
            else {
                if (gn + 0 < N) v.x = p[0];
                if (gn + 1 < N) v.y = p[1];
                if (gn + 2 < N) v.z = p[2];
                if (gn + 3 < N) v.w = p[3];
            }
        }
        tile[r][cb + j * 4 + 0] = v.x;
        tile[r][cb + j * 4 + 1] = v.y;
        tile[r][cb + j * 4 + 2] = v.z;
        tile[r][cb + j * 4 + 3] = v.w;
    }
    __syncthreads();
    int n = n0 + r;
#pragma unroll
    for (int j = 0; j < 2; ++j) {
        int kk = cb + j * 8;
        f16x8 o;
#pragma unroll
        for (int u = 0; u < 8; ++u) o[u] = (f16)tile[kk + u][r];
        if (n < Np) *(f16x8*)(d + (long)n * Kp + k0 + kk) = o;
    }
}

// z = mu + exp(ls) * eps  (permuted rows)
__global__ void k_z(const float* __restrict__ mu, const float* __restrict__ ls,
                    const float* __restrict__ eps, const int* __restrict__ perm,
                    f16* __restrict__ Z) {
    long gid = (long)blockIdx.x * 256 + threadIdx.x;
    int i = (int)(gid >> 7), c = (int)(gid & 127);
    int r = perm[i];
    float m = mu[(long)r * L_ + c];
    float l = ls[(long)r * L_ + c];
    Z[(long)i * L_ + c] = (f16)(m + __expf(l) * eps[(long)r * L_ + c]);
}

#define DSR(dst, addr, IMM) \
    asm volatile("ds_read_b128 %0, %1 offset:" #IMM : "=v"(dst) : "v"(addr))

// ---------------------------------------------------------------------------
// 256Mx128N, BK=64, triple-buffered, counted-vmcnt, 1 barrier/K-tile.
// 8 waves = 4M x 2N; per-wave 64x64 = acc[4][4] frags of 16x16 (f16 MFMA K=32).
// LDS buffer: A [256 rows][64 cols] at 0 (32KB), B [128][64] at 32768 (16KB).
// Row = 128B = 8 slots of 16B; slot XOR-swizzled with (row&7) (T2, both sides).
// Staging: 6 global_load_lds chunk-loads (A:4, B:2) of 8KB each per K-tile.
// Ledger: prologue stages kt0,kt1 (12); iter i stages kt i+2 (+6);
// end-of-iter vmcnt(6) drains kt i+1; vmcnt(0) only when no stages remain.
// ---------------------------------------------------------------------------
template <int EPI, bool GROUPED>
__global__ __launch_bounds__(512, 2)
void k_gemmB(const f16* __restrict__ A,
             const f16* __restrict__ W, long wstride,
             const float* __restrict__ bias, int bstride,
             int K, int N, int ntn,
             f16* __restrict__ outF16, float* __restrict__ o0,
             const int* __restrict__ ctrl, const int* __restrict__ perm) {
    extern __shared__ char lds[];
    int tid = threadIdx.x, lane = tid & 63;
    int wave = tid >> 6, wm = wave >> 1, wn = wave & 1;

    // T1: bijective XCD swizzle (m204), any grid size
    int nwg = gridDim.x, orig = blockIdx.x;
    int qq = nwg >> 3, rr8 = nwg & 7, xcd = orig & 7, idx = orig >> 3;
    int wgid = (xcd < rr8 ? xcd * (qq + 1) : rr8 * (qq + 1) + (xcd - rr8) * qq) + idx;
    int tm = wgid / ntn, tn = wgid - tm * ntn;

    int t, row0, mrows;
    if (GROUPED) {
        if (tm >= ctrl[C_NTILES2]) return;
        t = ctrl[C_TTASK2 + tm];
        row0 = ctrl[C_TROW2 + tm];
        mrows = min(256, ctrl[C_OFFS + t + 1] - row0);
    } else {
        t = 0; row0 = tm * 256; mrows = 256;
    }
    const f16* Wt = W + (long)t * wstride;
    const float* bt = bias + (long)t * bstride;
    int n0 = tn * 128;

    // staging invariants: thread g covers (row g>>3 within 64-row chunk,
    // LDS slot g&7); global 16B-chunk = slot ^ (row&7) (inverse swizzle).
    int rowc = tid >> 3;
    long srcElem = (long)rowc * K + (((tid & 7) ^ (rowc & 7)) << 3);
    int dstOff = wave << 10;   // wave-uniform; HW adds lane*16
    const f16* Abase = A + (long)row0 * K + srcElem;
    const f16* Bbase = Wt + (long)n0 * K + srcElem;

    f32x4 acc[4][4];
#pragma unroll
    for (int i = 0; i < 4; ++i)
#pragma unroll
        for (int j = 0; j < 4; ++j) acc[i][j] = (f32x4){0.f, 0.f, 0.f, 0.f};

    auto STAGE = [&](int buf, int kt) {
        const f16* a = Abase + kt * 64;
        const f16* b = Bbase + kt * 64;
        char* base = lds + buf * BUFB;
#pragma unroll
        for (int c = 0; c < 4; ++c)
            __builtin_amdgcn_global_load_lds(
                (const __attribute__((address_space(1))) unsigned int*)(a + (long)c * 64 * K),
                (__attribute__((address_space(3))) unsigned int*)(base + c * 8192 + dstOff), 16, 0, 0);
#pragma unroll
        for (int c = 0; c < 2; ++c)
            __builtin_amdgcn_global_load_lds(
                (const __attribute__((address_space(1))) unsigned int*)(b + (long)c * 64 * K),
                (__attribute__((address_space(3))) unsigned int*)(base + 32768 + c * 8192 + dstOff), 16, 0, 0);
    };

    // read addresses (byte): slot = ((kstep<<2)|(lane>>4)) ^ (lane&7);
    // kstep=1 address = kstep=0 address ^ 64. mi/nj handled by imm offset.
    int slot0 = ((lane >> 4) ^ (lane & 7)) << 4;
    int aoffB = (wm * 64 + (lane & 15)) * 128 + slot0;
    int boffB = 32768 + (wn * 64 + (lane & 15)) * 128 + slot0;

    int NI = K >> 6;
    STAGE(0, 0);
    STAGE(1, 1);
    asm volatile("s_waitcnt vmcnt(6)" ::: "memory");
    asm volatile("s_barrier" ::: "memory");

    int b0 = 0, b1 = 1, b2 = 2;
    for (int i = 0; i < NI; ++i) {
        if (i + 2 < NI) STAGE(b2, i + 2);

        int aadr = b0 * BUFB + aoffB;
        int badr = b0 * BUFB + boffB;
        int aadr2 = aadr ^ 64;
        int badr2 = badr ^ 64;
        i32x4 ra0[4], rb0[4], ra1[4], rb1[4];
        DSR(ra0[0], aadr, 0);    DSR(ra0[1], aadr, 2048);
        DSR(ra0[2], aadr, 4096); DSR(ra0[3], aadr, 6144);
        DSR(rb0[0], badr, 0);    DSR(rb0[1], badr, 2048);
        DSR(rb0[2], badr, 4096); DSR(rb0[3], badr, 6144);
        DSR(ra1[0], aadr2, 0);    DSR(ra1[1], aadr2, 2048);
        DSR(ra1[2], aadr2, 4096); DSR(ra1[3], aadr2, 6144);
        DSR(rb1[0], badr2, 0);    DSR(rb1[1], badr2, 2048);
        DSR(rb1[2], badr2, 4096); DSR(rb1[3], badr2, 6144);

        asm volatile("s_waitcnt lgkmcnt(8)" ::: "memory");
        __builtin_amdgcn_sched_barrier(0);
        __builtin_amdgcn_s_setprio(1);
#pragma unroll
        for (int mi = 0; mi < 4; ++mi)
#pragma unroll
            for (int nj = 0; nj < 4; ++nj)
                acc[mi][nj] = __builtin_amdgcn_mfma_f32_16x16x32_f16(
                    __builtin_bit_cast(f16x8, ra0[mi]), __builtin_bit_cast(f16x8, rb0[nj]),
                    acc[mi][nj], 0, 0, 0);
        __builtin_amdgcn_s_setprio(0);

        asm volatile("s_waitcnt lgkmcnt(0)" ::: "memory");
        __builtin_amdgcn_sched_barrier(0);
        __builtin_amdgcn_s_setprio(1);
#pragma unroll
        for (int mi = 0; mi < 4; ++mi)
#pragma unroll
            for (int nj = 0; nj < 4; ++nj)
                acc[mi][nj] = __builtin_amdgcn_mfma_f32_16x16x32_f16(
                    __builtin_bit_cast(f16x8, ra1[mi]), __builtin_bit_cast(f16x8, rb1[nj]),
                    acc[mi][nj], 0, 0, 0);
        __builtin_amdgcn_s_setprio(0);

        if (i + 1 < NI) {
            if (i + 2 < NI) asm volatile("s_waitcnt vmcnt(6)" ::: "memory");
            else            asm volatile("s_waitcnt vmcnt(0)" ::: "memory");
            asm volatile("s_barrier" ::: "memory");
        }
        int tmp = b0; b0 = b1; b1 = b2; b2 = tmp;
    }

    // epilogue
    int cq = lane >> 4, cr = lane & 15;
#pragma unroll
    for (int mi = 0; mi < 4; ++mi) {
#pragma unroll
        for (int nj = 0; nj < 4; ++nj) {
#pragma unroll
            for (int reg = 0; reg < 4; ++reg) {
                int rl = wm * 64 + mi * 16 + cq * 4 + reg;
                if (rl >= mrows) continue;
                int gcol = n0 + wn * 64 + nj * 16 + cr;
                if (gcol >= N) continue;
                float v = acc[mi][nj][reg] + bt[gcol];
                int grow = row0 + rl;
                if (EPI == 0) {
                    outF16[(long)grow * H_ + gcol] = (f16)(v > 0.f ? v : 0.f);
                } else {
                    o0[(long)perm[grow] * D_ + gcol] = 1.f / (1.f + __expf(-v));
                }
            }
        }
    }
}

// 128x128 2-phase kernel (enc3 only: N=256, EPI 1 mu/ls scatter).
template <int EPI, bool GROUPED>
__global__ __launch_bounds__(256)
void k_gemm(const f16* __restrict__ A,
            const f16* __restrict__ W, long wstride,
            const float* __restrict__ bias, int bstride,
            int K, int N,
            f16* __restrict__ outF16,
            float* __restrict__ o0, float* __restrict__ o1,
            const int* __restrict__ ctrl, const int* __restrict__ perm) {
    __shared__ f16 sA[2 * 8192];
    __shared__ f16 sB[2 * 8192];
    int tid = threadIdx.x;
    int lane = tid & 63, wave = tid >> 6;
    int wm = wave >> 1, wn = wave & 1;
    int n0 = blockIdx.x * 128;

    int t, row0, mrows;
    if (GROUPED) {
        int nt = ctrl[C_NTILES];
        if ((int)blockIdx.y >= nt) return;
        t = ctrl[C_TTASK + blockIdx.y];
        row0 = ctrl[C_TROW + blockIdx.y];
        mrows = min(128, ctrl[C_OFFS + t + 1] - row0);
    } else {
        t = 0; row0 = blockIdx.y * 128; mrows = 128;
    }
    const f16* Wt = W + (long)t * wstride;
    const float* bt = bias + (long)t * bstride;

    int srow = tid >> 3, scol = (tid & 7) << 3;

    f32x4 acc[4][4];
#pragma unroll
    for (int i = 0; i < 4; ++i)
#pragma unroll
        for (int j = 0; j < 4; ++j) acc[i][j] = (f32x4){0.f, 0.f, 0.f, 0.f};

    auto stage = [&](int buf, int kt) {
        int k0 = kt << 6;
        const f16* Ab = A + (long)row0 * K + k0;
        const f16* Bb = Wt + (long)n0 * K + k0;
#pragma unroll
        for (int rr = 0; rr < 4; ++rr) {
            __builtin_amdgcn_global_load_lds(
                (const __attribute__((address_space(1))) unsigned int*)(Ab + (long)(srow + 32 * rr) * K + scol),
                (__attribute__((address_space(3))) unsigned int*)(sA + buf * 8192 + rr * 2048 + wave * 512),
                16, 0, 0);
            __builtin_amdgcn_global_load_lds(
                (const __attribute__((address_space(1))) unsigned int*)(Bb + (long)(srow + 32 * rr) * K + scol),
                (__attribute__((address_space(3))) unsigned int*)(sB + buf * 8192 + rr * 2048 + wave * 512),
                16, 0, 0);
        }
    };

    auto compute = [&](int buf) {
        const f16* bA = sA + buf * 8192;
        const f16* bB = sB + buf * 8192;
#pragma unroll
        for (int kk = 0; kk < 2; ++kk) {
            f16x8 af[4], bf[4];
            int ko = kk * 32 + ((lane >> 4) << 3);
#pragma unroll
            for (int mi = 0; mi < 4; ++mi)
                af[mi] = *(const f16x8*)(bA + (wm * 64 + mi * 16 + (lane & 15)) * 64 + ko);
#pragma unroll
            for (int nj = 0; nj < 4; ++nj)
                bf[nj] = *(const f16x8*)(bB + (wn * 64 + nj * 16 + (lane & 15)) * 64 + ko);
#pragma unroll
            for (int mi = 0; mi < 4; ++mi)
#pragma unroll
                for (int nj = 0; nj < 4; ++nj)
                    acc[mi][nj] = __builtin_amdgcn_mfma_f32_16x16x32_f16(af[mi], bf[nj], acc[mi][nj], 0, 0, 0);
        }
    };

    int nk = K >> 6;
    stage(0, 0);
    __syncthreads();
    int cur = 0;
    for (int kt = 0; kt + 1 < nk; ++kt) {
        stage(cur ^ 1, kt + 1);
        compute(cur);
        __syncthreads();
        cur ^= 1;
    }
    compute(cur);

    int cq = lane >> 4;
    int cr = lane & 15;
#pragma unroll
    for (int mi = 0; mi < 4; ++mi) {
#pragma unroll
        for (int nj = 0; nj < 4; ++nj) {
#pragma unroll
            for (int reg = 0; reg < 4; ++reg) {
                int rl = wm * 64 + mi * 16 + cq * 4 + reg;
                int cl = wn * 64 + nj * 16 + cr;
                if (rl >= mrows) continue;
                int gcol = n0 + cl;
                if (gcol >= N) continue;
                float v = acc[mi][nj][reg] + bt[gcol];
                int grow = row0 + rl;
                if (EPI == 0) {
                    outF16[(long)grow * H_ + gcol] = (f16)(v > 0.f ? v : 0.f);
                } else if (EPI == 1) {
                    int r = perm[grow];
                    if (gcol < L_) o0[(long)r * L_ + gcol] = v;
                    else o1[(long)r * L_ + (gcol - L_)] = v;
                } else {
                    int r = perm[grow];
                    o0[(long)r * D_ + gcol] = 1.f / (1.f + __expf(-v));
                }
            }
        }
    }
}

extern "C" void kernel_launch(void* const* d_in, const int* in_sizes, int n_in,
                              void* d_out, int out_size, void* d_ws, size_t ws_size,
                              hipStream_t stream) {
    const float* x   = (const float*)d_in[0];
    const float* eps = (const float*)d_in[1];
    const float* eW1 = (const float*)d_in[2];
    const float* eb1 = (const float*)d_in[3];
    const float* eW2 = (const float*)d_in[4];
    const float* eb2 = (const float*)d_in[5];
    const float* eW3 = (const float*)d_in[6];
    const float* eb3 = (const float*)d_in[7];
    const float* dW1 = (const float*)d_in[8];
    const float* db1 = (const float*)d_in[9];
    const float* dW2 = (const float*)d_in[10];
    const float* db2 = (const float*)d_in[11];
    const float* hW  = (const float*)d_in[12];
    const float* hb  = (const float*)d_in[13];
    const int* task  = (const int*)d_in[14];

    float* out = (float*)d_out;
    float* recon = out;
    float* mu = out + (size_t)B_ * D_;
    float* ls = mu + (size_t)B_ * L_;

    char* w = (char*)d_ws;
    size_t o = 0;
    auto alloc = [&](size_t bytes) -> char* {
        char* p = w + o;
        o = (o + bytes + 255) & ~(size_t)255;
        return p;
    };
    int* ctrl  = (int*)alloc(4096);
    int* perm  = (int*)alloc((size_t)B_ * 4);
    f16* Xp    = (f16*)alloc((size_t)(B_ + PADROWS) * KP1 * 2);
    f16* H1    = (f16*)alloc((size_t)(B_ + PADROWS) * H_ * 2);
    f16* H2    = (f16*)alloc((size_t)(B_ + PADROWS) * H_ * 2);
    f16* Z     = (f16*)alloc((size_t)(B_ + PADROWS) * L_ * 2);
    f16* Wt1   = (f16*)alloc((size_t)T_ * H_ * KP1 * 2);
    f16* Wt2   = (f16*)alloc((size_t)T_ * H_ * H_ * 2);
    f16* Wt3   = (f16*)alloc((size_t)T_ * 256 * H_ * 2);
    f16* WtD1  = (f16*)alloc((size_t)H_ * L_ * 2);
    f16* WtD2  = (f16*)alloc((size_t)H_ * H_ * 2);
    f16* WtH   = (f16*)alloc((size_t)T_ * NPH * H_ * 2);
    if (o > ws_size) return;

    (void)hipFuncSetAttribute((const void*)&k_gemmB<0, true>,  hipFuncAttributeMaxDynamicSharedMemorySize, 3 * BUFB);
    (void)hipFuncSetAttribute((const void*)&k_gemmB<0, false>, hipFuncAttributeMaxDynamicSharedMemorySize, 3 * BUFB);
    (void)hipFuncSetAttribute((const void*)&k_gemmB<2, true>,  hipFuncAttributeMaxDynamicSharedMemorySize, 3 * BUFB);

    k_init<<<1, 64, 0, stream>>>(ctrl);
    k_count<<<B_ / 256, 256, 0, stream>>>(task, ctrl);
    k_scan<<<1, 1, 0, stream>>>(ctrl);
    k_scatter<<<B_ / 256, 256, 0, stream>>>(task, ctrl, perm);
    k_gather_x<<<B_, 256, 0, stream>>>(x, perm, Xp);

    k_convW<<<dim3(KP1 / 64, H_ / 64, T_), 256, 0, stream>>>(eW1, Wt1, D_, H_, KP1, H_);
    k_convW<<<dim3(H_ / 64, H_ / 64, T_), 256, 0, stream>>>(eW2, Wt2, H_, H_, H_, H_);
    k_convW<<<dim3(H_ / 64, 256 / 64, T_), 256, 0, stream>>>(eW3, Wt3, H_, 256, H_, 256);
    k_convW<<<dim3(L_ / 64, H_ / 64, 1), 256, 0, stream>>>(dW1, WtD1, L_, H_, L_, H_);
    k_convW<<<dim3(H_ / 64, H_ / 64, 1), 256, 0, stream>>>(dW2, WtD2, H_, H_, H_, H_);
    k_convW<<<dim3(H_ / 64, NPH / 64, T_), 256, 0, stream>>>(hW, WtH, H_, D_, H_, NPH);

    int gridG = MAXT256 * 8;       // 336 (grouped, 8 N-tiles)
    int gridD = (B_ / 256) * 8;    // 256 (dense, 8 N-tiles)
    int gridH = MAXT256 * 7;       // 294 (head, 7 N-tiles cover 896 >= 784)

    // encoder layer 1: Xp(K=896) @ Wt1 -> relu -> H1
    k_gemmB<0, true><<<gridG, 512, 3 * BUFB, stream>>>(
        Xp, Wt1, (long)H_ * KP1, eb1, H_, KP1, H_, 8, H1, nullptr, ctrl, perm);
    // encoder layer 2: H1 @ Wt2 -> relu -> H2
    k_gemmB<0, true><<<gridG, 512, 3 * BUFB, stream>>>(
        H1, Wt2, (long)H_ * H_, eb2, H_, H_, H_, 8, H2, nullptr, ctrl, perm);
    // encoder layer 3 (N=256): 128^2 kernel, mu/ls scatter
    k_gemm<1, true><<<dim3(256 / 128, MAXTILES), 256, 0, stream>>>(
        H2, Wt3, (long)256 * H_, eb3, 256, H_, 256, nullptr, mu, ls, ctrl, perm);
    // z = mu + exp(ls)*eps
    k_z<<<(B_ * L_) / 256, 256, 0, stream>>>(mu, ls, eps, perm, Z);
    // decoder layer 1: Z(K=128) @ WtD1 -> relu -> H1
    k_gemmB<0, false><<<gridD, 512, 3 * BUFB, stream>>>(
        Z, WtD1, 0, db1, 0, L_, H_, 8, H1, nullptr, ctrl, perm);
    // decoder layer 2: H1 @ WtD2 -> relu -> H2
    k_gemmB<0, false><<<gridD, 512, 3 * BUFB, stream>>>(
        H1, WtD2, 0, db2, 0, H_, H_, 8, H2, nullptr, ctrl, perm);
    // head: H2 @ WtH -> sigmoid -> recon (scatter fp32)
    k_gemmB<2, true><<<gridH, 512, 3 * BUFB, stream>>>(
        H2, WtH, (long)NPH * H_, hb, D_, H_, D_, 7, nullptr, recon, ctrl, perm);
}